// Round 5
// baseline (303.693 us; speedup 1.0000x reference)
//
#include <hip/hip_runtime.h>
#include <math.h>

#define L2E 1.4426950408889634f
#define XP  2112          // padded row stride for [chan][row] layouts
#define ATP 272           // attT stride in float4
#define SFP 320           // sfw/sbw stride in floats

static __device__ __forceinline__ float fexp2(float x) {
#if __has_builtin(__builtin_amdgcn_exp2f)
    return __builtin_amdgcn_exp2f(x);
#else
    return exp2f(x);
#endif
}
static __device__ __forceinline__ float frcp(float x) {
#if __has_builtin(__builtin_amdgcn_rcpf)
    return __builtin_amdgcn_rcpf(x);
#else
    return 1.0f / x;
#endif
}
static __device__ __forceinline__ float fsigmoid(float x) {
    return frcp(1.0f + fexp2(-x * L2E));
}

// ---------------------------------------------------------------------------
// kA: embedding gather -> xxT [200][XP]. 200 blocks x 256.
__global__ __launch_bounds__(256) void kA_gather(
    const int* __restrict__ x, const float* __restrict__ emb,
    float* __restrict__ xxT)
{
    const int gtid = blockIdx.x * 256 + threadIdx.x;
    const int unit = gtid >> 6;
    const int lane = threadIdx.x & 63;
    const int rowblk = unit & 31;
    int c0 = (unit >> 5) * 8;
    c0 = __builtin_amdgcn_readfirstlane(c0);
    const int row = (rowblk << 6) + lane;
    const int tok = x[row];
    float4 v0 = *(const float4*)&emb[(size_t)tok * 200 + c0];
    float4 v1 = *(const float4*)&emb[(size_t)tok * 200 + c0 + 4];
    xxT[(size_t)(c0 + 0) * XP + row] = v0.x;
    xxT[(size_t)(c0 + 1) * XP + row] = v0.y;
    xxT[(size_t)(c0 + 2) * XP + row] = v0.z;
    xxT[(size_t)(c0 + 3) * XP + row] = v0.w;
    xxT[(size_t)(c0 + 4) * XP + row] = v1.x;
    xxT[(size_t)(c0 + 5) * XP + row] = v1.y;
    xxT[(size_t)(c0 + 6) * XP + row] = v1.z;
    xxT[(size_t)(c0 + 7) * XP + row] = v1.w;
}

// ---------------------------------------------------------------------------
// kB: h = elu(xx @ Wh + b) -> hT [200][XP].
// grid (25 colblk, 8 rowtile) x 512: 256 rows x 2 col-halves, 4 cols/thread.
__global__ __launch_bounds__(512) void kB_h(
    const float* __restrict__ xxT, const float* __restrict__ Wh_w,
    const float* __restrict__ Wh_b, float* __restrict__ hT)
{
    __shared__ float4 wl[200][2];
    const int tid = threadIdx.x;
    const int rloc = tid & 255;
    const int half = tid >> 8;
    const int row = blockIdx.y * 256 + rloc;
    const int cb = blockIdx.x * 8;
    const int c0 = cb + half * 4;
    for (int i = tid; i < 400; i += 512) {
        int k = i >> 1, part = i & 1;
        wl[k][part] = *(const float4*)&Wh_w[(size_t)k * 200 + cb + part * 4];
    }
    __syncthreads();
    float4 bias = *(const float4*)&Wh_b[c0];
    float a0 = bias.x, a1 = bias.y, a2 = bias.z, a3 = bias.w;
    const float* ap = xxT + row;
#pragma unroll 8
    for (int k = 0; k < 200; k++) {
        float av = ap[(size_t)k * XP];
        float4 w = wl[k][half];
        a0 = fmaf(av, w.x, a0);
        a1 = fmaf(av, w.y, a1);
        a2 = fmaf(av, w.z, a2);
        a3 = fmaf(av, w.w, a3);
    }
    hT[(size_t)(c0 + 0) * XP + row] = a0 > 0.0f ? a0 : expm1f(a0);
    hT[(size_t)(c0 + 1) * XP + row] = a1 > 0.0f ? a1 : expm1f(a1);
    hT[(size_t)(c0 + 2) * XP + row] = a2 > 0.0f ? a2 : expm1f(a2);
    hT[(size_t)(c0 + 3) * XP + row] = a3 > 0.0f ? a3 : expm1f(a3);
}

// ---------------------------------------------------------------------------
// kC: h1=h@W1, h2b=h@W2+b -> attT[(b*200+e)][l] = (E, D, h, F)
// grid (25, 8) x 512
__global__ __launch_bounds__(512) void kC_h12(
    const float* __restrict__ hT, const float* __restrict__ W1_w,
    const float* __restrict__ W2_w, const float* __restrict__ bvec,
    const float* __restrict__ xxT, const float* __restrict__ cptr,
    float4* __restrict__ attT)
{
    __shared__ float4 wl1[200][2];
    __shared__ float4 wl2[200][2];
    const int tid = threadIdx.x;
    const int rloc = tid & 255;
    const int half = tid >> 8;
    const int b = blockIdx.y;
    const int row = b * 256 + rloc;
    const int cb = blockIdx.x * 8;
    const int c0 = cb + half * 4;
    for (int i = tid; i < 400; i += 512) {
        int k = i >> 1, part = i & 1;
        wl1[k][part] = *(const float4*)&W1_w[(size_t)k * 200 + cb + part * 4];
        wl2[k][part] = *(const float4*)&W2_w[(size_t)k * 200 + cb + part * 4];
    }
    __syncthreads();
    float4 bias = *(const float4*)&bvec[c0];
    float s10 = 0, s11 = 0, s12 = 0, s13 = 0;
    float s20 = bias.x, s21 = bias.y, s22 = bias.z, s23 = bias.w;
    const float* ap = hT + row;
#pragma unroll 8
    for (int k = 0; k < 200; k++) {
        float av = ap[(size_t)k * XP];
        float4 w1 = wl1[k][half];
        float4 w2 = wl2[k][half];
        s10 = fmaf(av, w1.x, s10); s20 = fmaf(av, w2.x, s20);
        s11 = fmaf(av, w1.y, s11); s21 = fmaf(av, w2.y, s21);
        s12 = fmaf(av, w1.z, s12); s22 = fmaf(av, w2.z, s22);
        s13 = fmaf(av, w1.w, s13); s23 = fmaf(av, w2.w, s23);
    }
    const float cval = cptr[0];
    const float S = 2.0f * L2E / cval;
    const float negC = -2.0f * cval * L2E;
    float s1a[4] = {s10, s11, s12, s13};
    float s2a[4] = {s20, s21, s22, s23};
#pragma unroll
    for (int j = 0; j < 4; j++) {
        float E = fexp2(S * s2a[j]);
        float F = fexp2(S * s1a[j]);
        float xv = xxT[(size_t)(c0 + j) * XP + row];
        float hv = hT[(size_t)(c0 + j) * XP + row];
        float D = (xv == 1.0f) ? -__builtin_huge_valf() : negC;  // faithful mask
        attT[(size_t)(b * 200 + c0 + j) * ATP + rloc] = make_float4(E, D, hv, F);
    }
}

// ---------------------------------------------------------------------------
// k2: per-channel masked double softmax. Block = channel, thread = t.
// p(t,m) = exp2(rcp(fma(F_t,E_m,1)) * D_m). grid 1600 x 256
__global__ __launch_bounds__(256) void k2_attn(
    const float4* __restrict__ attT,
    float* __restrict__ sfwT, float* __restrict__ sbwT)
{
    __shared__ float4 pk[256];
    __shared__ float hpart[4];
    const int ch = blockIdx.x;
    const int t = threadIdx.x;
    const int lane = t & 63;
    const int wv = t >> 6;
    float4 own = attT[(size_t)ch * ATP + t];
    pk[t] = own;
    // block-wide hsum (same for all t)
    float hv = own.z;
#pragma unroll
    for (int off = 32; off > 0; off >>= 1) hv += __shfl_xor(hv, off, 64);
    if (lane == 0) hpart[wv] = hv;
    __syncthreads();
    const float hsum = hpart[0] + hpart[1] + hpart[2] + hpart[3];
    const float F = own.w;
    float sumf = 0.0f, accf = 0.0f, sumb = 0.0f, accb = 0.0f;
#pragma unroll 8
    for (int m = 0; m < 256; m++) {
        float4 pm = pk[m];
        float r = frcp(fmaf(F, pm.x, 1.0f));
        float p = fexp2(r * pm.y);
        float qf = (m > t) ? p : 0.0f;
        float qb = (m < t) ? p : 0.0f;
        sumf += qf; accf = fmaf(qf, pm.z, accf);
        sumb += qb; accb = fmaf(qb, pm.z, accb);
    }
    float uni = hsum * (1.0f / 256.0f);
    bool selfm = own.y < -3.0e38f;
    sfwT[(size_t)ch * SFP + t] = (selfm || sumf == 0.0f) ? uni : accf / sumf;
    sbwT[(size_t)ch * SFP + t] = (selfm || sumb == 0.0f) ? uni : accb / sumb;
}

// ---------------------------------------------------------------------------
// kD: gf=sfw@Wf1, gb=sbw@Wf1, g2=h@Wf2+b; u -> uuT[400][XP]. grid (25,8) x 512
__global__ __launch_bounds__(512) void kD_gate(
    const float* __restrict__ hT, const float* __restrict__ sfwT,
    const float* __restrict__ sbwT, const float* __restrict__ Wf1,
    const float* __restrict__ Wf2, const float* __restrict__ Wf2_b,
    float* __restrict__ uuT)
{
    __shared__ float4 wl1[200][2];
    __shared__ float4 wl2[200][2];
    const int tid = threadIdx.x;
    const int rloc = tid & 255;
    const int half = tid >> 8;
    const int b = blockIdx.y;
    const int row = b * 256 + rloc;
    const int cb = blockIdx.x * 8;
    const int c0 = cb + half * 4;
    for (int i = tid; i < 400; i += 512) {
        int k = i >> 1, part = i & 1;
        wl1[k][part] = *(const float4*)&Wf1[(size_t)k * 200 + cb + part * 4];
        wl2[k][part] = *(const float4*)&Wf2[(size_t)k * 200 + cb + part * 4];
    }
    __syncthreads();
    float4 bias = *(const float4*)&Wf2_b[c0];
    float gf0 = 0, gf1 = 0, gf2 = 0, gf3 = 0;
    float gb0 = 0, gb1 = 0, gb2 = 0, gb3 = 0;
    float g20 = bias.x, g21 = bias.y, g22 = bias.z, g23 = bias.w;
    const float* hp = hT + row;
    const float* fp = sfwT + (size_t)b * 200 * SFP + rloc;
    const float* bp = sbwT + (size_t)b * 200 * SFP + rloc;
#pragma unroll 4
    for (int k = 0; k < 200; k++) {
        float hvv = hp[(size_t)k * XP];
        float fv = fp[(size_t)k * SFP];
        float bv = bp[(size_t)k * SFP];
        float4 w1 = wl1[k][half];
        float4 w2 = wl2[k][half];
        gf0 = fmaf(fv, w1.x, gf0); gb0 = fmaf(bv, w1.x, gb0); g20 = fmaf(hvv, w2.x, g20);
        gf1 = fmaf(fv, w1.y, gf1); gb1 = fmaf(bv, w1.y, gb1); g21 = fmaf(hvv, w2.y, g21);
        gf2 = fmaf(fv, w1.z, gf2); gb2 = fmaf(bv, w1.z, gb2); g22 = fmaf(hvv, w2.z, g22);
        gf3 = fmaf(fv, w1.w, gf3); gb3 = fmaf(bv, w1.w, gb3); g23 = fmaf(hvv, w2.w, g23);
    }
    float gfa[4] = {gf0, gf1, gf2, gf3};
    float gba[4] = {gb0, gb1, gb2, gb3};
    float g2a[4] = {g20, g21, g22, g23};
#pragma unroll
    for (int j = 0; j < 4; j++) {
        float hvv = hT[(size_t)(c0 + j) * XP + row];
        float sfo = sfwT[(size_t)(b * 200 + c0 + j) * SFP + rloc];
        float sbo = sbwT[(size_t)(b * 200 + c0 + j) * SFP + rloc];
        float ff = fsigmoid(gfa[j] + g2a[j]);
        float fb = fsigmoid(gba[j] + g2a[j]);
        uuT[(size_t)(c0 + j) * XP + row]       = ff * hvv + (1.0f - ff) * sfo;
        uuT[(size_t)(200 + c0 + j) * XP + row] = fb * hvv + (1.0f - fb) * sbo;
    }
}

// ---------------------------------------------------------------------------
// kE: t1 = elu(uu @ Ws1 + b1) -> t1T [400][XP]. grid (25,8) x 512, 8 cols/thr
__global__ __launch_bounds__(512) void kE_t1(
    const float* __restrict__ uuT, const float* __restrict__ Ws1_w,
    const float* __restrict__ Ws1_b, float* __restrict__ t1T)
{
    __shared__ float4 wl[400][4];
    const int tid = threadIdx.x;
    const int rloc = tid & 255;
    const int half = tid >> 8;
    const int row = blockIdx.y * 256 + rloc;
    const int cb = blockIdx.x * 16;
    const int c0 = cb + half * 8;
    for (int i = tid; i < 1600; i += 512) {
        int k = i >> 2, part = i & 3;
        wl[k][part] = *(const float4*)&Ws1_w[(size_t)k * 400 + cb + part * 4];
    }
    __syncthreads();
    float acc[8];
#pragma unroll
    for (int j = 0; j < 8; j++) acc[j] = Ws1_b[c0 + j];
    const float* ap = uuT + row;
#pragma unroll 4
    for (int k = 0; k < 400; k++) {
        float av = ap[(size_t)k * XP];
        float4 wa = wl[k][half * 2];
        float4 wb = wl[k][half * 2 + 1];
        acc[0] = fmaf(av, wa.x, acc[0]);
        acc[1] = fmaf(av, wa.y, acc[1]);
        acc[2] = fmaf(av, wa.z, acc[2]);
        acc[3] = fmaf(av, wa.w, acc[3]);
        acc[4] = fmaf(av, wb.x, acc[4]);
        acc[5] = fmaf(av, wb.y, acc[5]);
        acc[6] = fmaf(av, wb.z, acc[6]);
        acc[7] = fmaf(av, wb.w, acc[7]);
    }
#pragma unroll
    for (int j = 0; j < 8; j++) {
        float a = acc[j];
        t1T[(size_t)(c0 + j) * XP + row] = a > 0.0f ? a : expm1f(a);
    }
}

// ---------------------------------------------------------------------------
// kF: att_s = t1 @ Ws + b2; s_s[b,col] += sum_rows uu*att_s. grid (25,8) x 512
__global__ __launch_bounds__(512) void kF_pool(
    const float* __restrict__ t1T, const float* __restrict__ Ws_w,
    const float* __restrict__ Ws_b, const float* __restrict__ uuT,
    float* __restrict__ s_s)
{
    __shared__ float4 wl[400][4];
    const int tid = threadIdx.x;
    const int rloc = tid & 255;
    const int half = tid >> 8;
    const int lane = tid & 63;
    const int b = blockIdx.y;
    const int row = b * 256 + rloc;
    const int cb = blockIdx.x * 16;
    const int c0 = cb + half * 8;
    for (int i = tid; i < 1600; i += 512) {
        int k = i >> 2, part = i & 3;
        wl[k][part] = *(const float4*)&Ws_w[(size_t)k * 400 + cb + part * 4];
    }
    __syncthreads();
    float acc[8];
#pragma unroll
    for (int j = 0; j < 8; j++) acc[j] = Ws_b[c0 + j];
    const float* ap = t1T + row;
#pragma unroll 4
    for (int k = 0; k < 400; k++) {
        float av = ap[(size_t)k * XP];
        float4 wa = wl[k][half * 2];
        float4 wb = wl[k][half * 2 + 1];
        acc[0] = fmaf(av, wa.x, acc[0]);
        acc[1] = fmaf(av, wa.y, acc[1]);
        acc[2] = fmaf(av, wa.z, acc[2]);
        acc[3] = fmaf(av, wa.w, acc[3]);
        acc[4] = fmaf(av, wb.x, acc[4]);
        acc[5] = fmaf(av, wb.y, acc[5]);
        acc[6] = fmaf(av, wb.z, acc[6]);
        acc[7] = fmaf(av, wb.w, acc[7]);
    }
#pragma unroll
    for (int j = 0; j < 8; j++) {
        float v = acc[j] * uuT[(size_t)(c0 + j) * XP + row];
#pragma unroll
        for (int off = 32; off > 0; off >>= 1) v += __shfl_xor(v, off, 64);
        if (lane == 0) atomicAdd(&s_s[b * 400 + c0 + j], v);
    }
}

// ---------------------------------------------------------------------------
// k5: y = relu(s_s@F1+b)@F2+b2. grid 8 x 256
__global__ __launch_bounds__(256) void k5_final(
    const float* __restrict__ s_s, const float* __restrict__ F1_w,
    const float* __restrict__ F1_b, const float* __restrict__ F2_w,
    const float* __restrict__ F2_b, float* __restrict__ y)
{
    const int b = blockIdx.x;
    const int e = threadIdx.x;
    __shared__ float red[256];
    float val = 0.0f;
    if (e < 200) {
        float a = F1_b[e];
#pragma unroll 8
        for (int k = 0; k < 400; k++)
            a = fmaf(s_s[b * 400 + k], F1_w[(size_t)k * 200 + e], a);
        a = a > 0.0f ? a : 0.0f;
        val = a * F2_w[e];
    }
    red[e] = val;
    __syncthreads();
    for (int s = 128; s > 0; s >>= 1) {
        if (e < s) red[e] += red[e + s];
        __syncthreads();
    }
    if (e == 0) y[b] = red[0] + F2_b[0];
}

extern "C" void kernel_launch(void* const* d_in, const int* in_sizes, int n_in,
                              void* d_out, int out_size, void* d_ws, size_t ws_size,
                              hipStream_t stream)
{
    const int*   x     = (const int*)  d_in[0];
    const float* emb   = (const float*)d_in[1];
    const float* Wh_w  = (const float*)d_in[2];
    const float* Wh_b  = (const float*)d_in[3];
    const float* W1_w  = (const float*)d_in[4];
    const float* W2_w  = (const float*)d_in[5];
    const float* bvec  = (const float*)d_in[6];
    const float* cptr  = (const float*)d_in[7];
    const float* Wf1_w = (const float*)d_in[8];
    const float* Wf2_w = (const float*)d_in[9];
    const float* Wf2_b = (const float*)d_in[10];
    const float* Ws1_w = (const float*)d_in[11];
    const float* Ws1_b = (const float*)d_in[12];
    const float* Ws_w  = (const float*)d_in[13];
    const float* Ws_b  = (const float*)d_in[14];
    const float* F1_w  = (const float*)d_in[15];
    const float* F1_b  = (const float*)d_in[16];
    const float* F2_w  = (const float*)d_in[17];
    const float* F2_b  = (const float*)d_in[18];
    float* out = (float*)d_out;

    char* ws = (char*)d_ws;
    float*  xxT  = (float*) (ws + 0);          // 200*2112*4 = 1,689,600
    float*  hT   = (float*) (ws + 1689600);    // 1,689,600
    float4* attT = (float4*)(ws + 3379200);    // 1600*272*16 = 6,963,200
    float*  sfwT = (float*) (ws + 10342400);   // 1600*320*4 = 2,048,000
    float*  sbwT = (float*) (ws + 12390400);   // 2,048,000
    float*  uuT  = (float*) (ws + 14438400);   // 400*2112*4 = 3,379,200
    float*  t1T  = (float*) (ws + 17817600);   // 3,379,200
    float*  s_s  = (float*) (ws + 21196800);   // 12,800

    hipMemsetAsync(s_s, 0, 8 * 400 * sizeof(float), stream);

    hipLaunchKernelGGL(kA_gather, dim3(200),    dim3(256), 0, stream, x, emb, xxT);
    hipLaunchKernelGGL(kB_h,      dim3(25, 8),  dim3(512), 0, stream, xxT, Wh_w, Wh_b, hT);
    hipLaunchKernelGGL(kC_h12,    dim3(25, 8),  dim3(512), 0, stream,
                       hT, W1_w, W2_w, bvec, xxT, cptr, attT);
    hipLaunchKernelGGL(k2_attn,   dim3(1600),   dim3(256), 0, stream,
                       attT, sfwT, sbwT);
    hipLaunchKernelGGL(kD_gate,   dim3(25, 8),  dim3(512), 0, stream,
                       hT, sfwT, sbwT, Wf1_w, Wf2_w, Wf2_b, uuT);
    hipLaunchKernelGGL(kE_t1,     dim3(25, 8),  dim3(512), 0, stream,
                       uuT, Ws1_w, Ws1_b, t1T);
    hipLaunchKernelGGL(kF_pool,   dim3(25, 8),  dim3(512), 0, stream,
                       t1T, Ws_w, Ws_b, uuT, s_s);
    hipLaunchKernelGGL(k5_final,  dim3(8),      dim3(256), 0, stream,
                       s_s, F1_w, F1_b, F2_w, F2_b, out);
}

// Round 7
// 273.308 us; speedup vs baseline: 1.1112x; 1.1112x over previous
//
#include <hip/hip_runtime.h>
#include <math.h>

#define L2E 1.4426950408889634f
#define XP  2112          // padded row stride for [chan][row] layouts
#define ATP 272           // attT stride in float4
#define SFP 320           // sfw/sbw stride in floats

static __device__ __forceinline__ float fexp2(float x) {
#if __has_builtin(__builtin_amdgcn_exp2f)
    return __builtin_amdgcn_exp2f(x);
#else
    return exp2f(x);
#endif
}
static __device__ __forceinline__ float frcp(float x) {
#if __has_builtin(__builtin_amdgcn_rcpf)
    return __builtin_amdgcn_rcpf(x);
#else
    return 1.0f / x;
#endif
}
static __device__ __forceinline__ float fsigmoid(float x) {
    return frcp(1.0f + fexp2(-x * L2E));
}

// All grids are 1-D; rowtile (== batch) = blockIdx.x & 7 so that workgroup i
// lands on XCD i%8 and batch b's intermediates stay in XCD b's L2 across the
// whole kernel chain (producer/consumer XCD pinning).

// ---------------------------------------------------------------------------
// kA: embedding gather -> xxT [200][XP]. 200 blocks: rt=blk&7, colgrp=blk>>3.
__global__ __launch_bounds__(256) void kA_gather(
    const int* __restrict__ x, const float* __restrict__ emb,
    float* __restrict__ xxT)
{
    const int blk = blockIdx.x;
    const int rt = blk & 7;
    const int c0 = (blk >> 3) * 8;
    const int row = rt * 256 + threadIdx.x;
    const int tok = x[row];
    float4 v0 = *(const float4*)&emb[(size_t)tok * 200 + c0];
    float4 v1 = *(const float4*)&emb[(size_t)tok * 200 + c0 + 4];
    xxT[(size_t)(c0 + 0) * XP + row] = v0.x;
    xxT[(size_t)(c0 + 1) * XP + row] = v0.y;
    xxT[(size_t)(c0 + 2) * XP + row] = v0.z;
    xxT[(size_t)(c0 + 3) * XP + row] = v0.w;
    xxT[(size_t)(c0 + 4) * XP + row] = v1.x;
    xxT[(size_t)(c0 + 5) * XP + row] = v1.y;
    xxT[(size_t)(c0 + 6) * XP + row] = v1.z;
    xxT[(size_t)(c0 + 7) * XP + row] = v1.w;
}

// ---------------------------------------------------------------------------
// kB: h = elu(xx @ Wh + b) -> hT [200][XP]. 800 blocks: rt=blk&7, 2 cols.
__global__ __launch_bounds__(256) void kB_h(
    const float* __restrict__ xxT, const float* __restrict__ Wh_w,
    const float* __restrict__ Wh_b, float* __restrict__ hT)
{
    __shared__ float2 wl[200];
    const int blk = blockIdx.x;
    const int rt = blk & 7;
    const int c0 = (blk >> 3) * 2;
    const int tid = threadIdx.x;
    const int row = rt * 256 + tid;
    if (tid < 200) wl[tid] = *(const float2*)&Wh_w[(size_t)tid * 200 + c0];
    __syncthreads();
    float a0 = Wh_b[c0], a1 = Wh_b[c0 + 1];
    const float* ap = xxT + row;
#pragma unroll 8
    for (int k = 0; k < 200; k++) {
        float av = ap[(size_t)k * XP];
        float2 w = wl[k];
        a0 = fmaf(av, w.x, a0);
        a1 = fmaf(av, w.y, a1);
    }
    hT[(size_t)(c0 + 0) * XP + row] = a0 > 0.0f ? a0 : expm1f(a0);
    hT[(size_t)(c0 + 1) * XP + row] = a1 > 0.0f ? a1 : expm1f(a1);
}

// ---------------------------------------------------------------------------
// kC: h1=h@W1, h2b=h@W2+b -> attT[(rt*200+e)][l] = (E, D, h, F). 800 blocks.
__global__ __launch_bounds__(256) void kC_h12(
    const float* __restrict__ hT, const float* __restrict__ W1_w,
    const float* __restrict__ W2_w, const float* __restrict__ bvec,
    const float* __restrict__ xxT, const float* __restrict__ cptr,
    float4* __restrict__ attT)
{
    __shared__ float2 wl1[200];
    __shared__ float2 wl2[200];
    const int blk = blockIdx.x;
    const int rt = blk & 7;           // batch
    const int c0 = (blk >> 3) * 2;
    const int tid = threadIdx.x;
    const int row = rt * 256 + tid;
    if (tid < 200) {
        wl1[tid] = *(const float2*)&W1_w[(size_t)tid * 200 + c0];
        wl2[tid] = *(const float2*)&W2_w[(size_t)tid * 200 + c0];
    }
    __syncthreads();
    float s10 = 0.0f, s11 = 0.0f;
    float s20 = bvec[c0], s21 = bvec[c0 + 1];
    const float* ap = hT + row;
#pragma unroll 8
    for (int k = 0; k < 200; k++) {
        float av = ap[(size_t)k * XP];
        float2 w1 = wl1[k];
        float2 w2 = wl2[k];
        s10 = fmaf(av, w1.x, s10); s20 = fmaf(av, w2.x, s20);
        s11 = fmaf(av, w1.y, s11); s21 = fmaf(av, w2.y, s21);
    }
    const float cval = cptr[0];
    const float S = 2.0f * L2E / cval;
    const float negC = -2.0f * cval * L2E;
    float s1a[2] = {s10, s11};
    float s2a[2] = {s20, s21};
#pragma unroll
    for (int j = 0; j < 2; j++) {
        float E = fexp2(S * s2a[j]);
        float F = fexp2(S * s1a[j]);
        float xv = xxT[(size_t)(c0 + j) * XP + row];
        float hv = hT[(size_t)(c0 + j) * XP + row];
        float D = (xv == 1.0f) ? -__builtin_huge_valf() : negC;  // faithful mask
        attT[(size_t)(rt * 200 + c0 + j) * ATP + tid] = make_float4(E, D, hv, F);
    }
}

// ---------------------------------------------------------------------------
// k2: per-channel masked double softmax. 1600 blocks; ch=(blk&7)*200+(blk>>3)
// keeps channel ch on the XCD that wrote it (batch = ch/200 = blk&7).
__global__ __launch_bounds__(256) void k2_attn(
    const float4* __restrict__ attT,
    float* __restrict__ sfwT, float* __restrict__ sbwT)
{
    __shared__ float4 pk[256];
    __shared__ float hpart[4];
    const int blk = blockIdx.x;
    const int ch = (blk & 7) * 200 + (blk >> 3);
    const int t = threadIdx.x;
    const int lane = t & 63;
    const int wv = t >> 6;
    float4 own = attT[(size_t)ch * ATP + t];
    pk[t] = own;
    float hv = own.z;
#pragma unroll
    for (int off = 32; off > 0; off >>= 1) hv += __shfl_xor(hv, off, 64);
    if (lane == 0) hpart[wv] = hv;
    __syncthreads();
    const float hsum = hpart[0] + hpart[1] + hpart[2] + hpart[3];
    const float F = own.w;
    float sumf = 0.0f, accf = 0.0f, sumb = 0.0f, accb = 0.0f;
#pragma unroll 8
    for (int m = 0; m < 256; m++) {
        float4 pm = pk[m];
        float r = frcp(fmaf(F, pm.x, 1.0f));
        float p = fexp2(r * pm.y);
        float qf = (m > t) ? p : 0.0f;
        float qb = (m < t) ? p : 0.0f;
        sumf += qf; accf = fmaf(qf, pm.z, accf);
        sumb += qb; accb = fmaf(qb, pm.z, accb);
    }
    float uni = hsum * (1.0f / 256.0f);
    bool selfm = own.y < -3.0e38f;
    sfwT[(size_t)ch * SFP + t] = (selfm || sumf == 0.0f) ? uni : accf / sumf;
    sbwT[(size_t)ch * SFP + t] = (selfm || sumb == 0.0f) ? uni : accb / sumb;
}

// ---------------------------------------------------------------------------
// kD: gf=sfw@Wf1, gb=sbw@Wf1, g2=h@Wf2+b; u -> uuT[400][XP]. 800 blocks.
__global__ __launch_bounds__(256) void kD_gate(
    const float* __restrict__ hT, const float* __restrict__ sfwT,
    const float* __restrict__ sbwT, const float* __restrict__ Wf1,
    const float* __restrict__ Wf2, const float* __restrict__ Wf2_b,
    float* __restrict__ uuT)
{
    __shared__ float2 wl1[200];
    __shared__ float2 wl2[200];
    const int blk = blockIdx.x;
    const int rt = blk & 7;           // batch
    const int c0 = (blk >> 3) * 2;
    const int tid = threadIdx.x;
    const int row = rt * 256 + tid;
    if (tid < 200) {
        wl1[tid] = *(const float2*)&Wf1[(size_t)tid * 200 + c0];
        wl2[tid] = *(const float2*)&Wf2[(size_t)tid * 200 + c0];
    }
    __syncthreads();
    float gf0 = 0, gf1 = 0, gb0 = 0, gb1 = 0;
    float g20 = Wf2_b[c0], g21 = Wf2_b[c0 + 1];
    const float* hp = hT + row;
    const float* fp = sfwT + (size_t)rt * 200 * SFP + tid;
    const float* bp = sbwT + (size_t)rt * 200 * SFP + tid;
#pragma unroll 4
    for (int k = 0; k < 200; k++) {
        float hvv = hp[(size_t)k * XP];
        float fv = fp[(size_t)k * SFP];
        float bv = bp[(size_t)k * SFP];
        float2 w1 = wl1[k];
        float2 w2 = wl2[k];
        gf0 = fmaf(fv, w1.x, gf0); gb0 = fmaf(bv, w1.x, gb0); g20 = fmaf(hvv, w2.x, g20);
        gf1 = fmaf(fv, w1.y, gf1); gb1 = fmaf(bv, w1.y, gb1); g21 = fmaf(hvv, w2.y, g21);
    }
    float gfa[2] = {gf0, gf1};
    float gba[2] = {gb0, gb1};
    float g2a[2] = {g20, g21};
#pragma unroll
    for (int j = 0; j < 2; j++) {
        float hvv = hT[(size_t)(c0 + j) * XP + row];
        float sfo = sfwT[(size_t)(rt * 200 + c0 + j) * SFP + tid];
        float sbo = sbwT[(size_t)(rt * 200 + c0 + j) * SFP + tid];
        float ff = fsigmoid(gfa[j] + g2a[j]);
        float fb = fsigmoid(gba[j] + g2a[j]);
        uuT[(size_t)(c0 + j) * XP + row]       = ff * hvv + (1.0f - ff) * sfo;
        uuT[(size_t)(200 + c0 + j) * XP + row] = fb * hvv + (1.0f - fb) * sbo;
    }
}

// ---------------------------------------------------------------------------
// kE: t1 = elu(uu @ Ws1 + b1) -> t1T [400][XP]. 800 blocks: rt=blk&7, 4 cols.
__global__ __launch_bounds__(256) void kE_t1(
    const float* __restrict__ uuT, const float* __restrict__ Ws1_w,
    const float* __restrict__ Ws1_b, float* __restrict__ t1T)
{
    __shared__ float4 wl[400];
    const int blk = blockIdx.x;
    const int rt = blk & 7;
    const int c0 = (blk >> 3) * 4;
    const int tid = threadIdx.x;
    const int row = rt * 256 + tid;
    for (int i = tid; i < 400; i += 256)
        wl[i] = *(const float4*)&Ws1_w[(size_t)i * 400 + c0];
    __syncthreads();
    float a0 = Ws1_b[c0], a1 = Ws1_b[c0 + 1], a2 = Ws1_b[c0 + 2], a3 = Ws1_b[c0 + 3];
    const float* ap = uuT + row;
#pragma unroll 8
    for (int k = 0; k < 400; k++) {
        float av = ap[(size_t)k * XP];
        float4 w = wl[k];
        a0 = fmaf(av, w.x, a0);
        a1 = fmaf(av, w.y, a1);
        a2 = fmaf(av, w.z, a2);
        a3 = fmaf(av, w.w, a3);
    }
    t1T[(size_t)(c0 + 0) * XP + row] = a0 > 0.0f ? a0 : expm1f(a0);
    t1T[(size_t)(c0 + 1) * XP + row] = a1 > 0.0f ? a1 : expm1f(a1);
    t1T[(size_t)(c0 + 2) * XP + row] = a2 > 0.0f ? a2 : expm1f(a2);
    t1T[(size_t)(c0 + 3) * XP + row] = a3 > 0.0f ? a3 : expm1f(a3);
}

// ---------------------------------------------------------------------------
// kF: att_s = t1 @ Ws + b2; s_s[rt,col] += sum_rows uu*att_s. 800 blocks.
__global__ __launch_bounds__(256) void kF_pool(
    const float* __restrict__ t1T, const float* __restrict__ Ws_w,
    const float* __restrict__ Ws_b, const float* __restrict__ uuT,
    float* __restrict__ s_s)
{
    __shared__ float4 wl[400];
    const int blk = blockIdx.x;
    const int rt = blk & 7;           // batch
    const int c0 = (blk >> 3) * 4;
    const int tid = threadIdx.x;
    const int lane = tid & 63;
    const int row = rt * 256 + tid;
    for (int i = tid; i < 400; i += 256)
        wl[i] = *(const float4*)&Ws_w[(size_t)i * 400 + c0];
    __syncthreads();
    float a0 = Ws_b[c0], a1 = Ws_b[c0 + 1], a2 = Ws_b[c0 + 2], a3 = Ws_b[c0 + 3];
    const float* ap = t1T + row;
#pragma unroll 8
    for (int k = 0; k < 400; k++) {
        float av = ap[(size_t)k * XP];
        float4 w = wl[k];
        a0 = fmaf(av, w.x, a0);
        a1 = fmaf(av, w.y, a1);
        a2 = fmaf(av, w.z, a2);
        a3 = fmaf(av, w.w, a3);
    }
    float v0 = a0 * uuT[(size_t)(c0 + 0) * XP + row];
    float v1 = a1 * uuT[(size_t)(c0 + 1) * XP + row];
    float v2 = a2 * uuT[(size_t)(c0 + 2) * XP + row];
    float v3 = a3 * uuT[(size_t)(c0 + 3) * XP + row];
#pragma unroll
    for (int off = 32; off > 0; off >>= 1) {
        v0 += __shfl_xor(v0, off, 64);
        v1 += __shfl_xor(v1, off, 64);
        v2 += __shfl_xor(v2, off, 64);
        v3 += __shfl_xor(v3, off, 64);
    }
    if (lane == 0) {
        atomicAdd(&s_s[rt * 400 + c0 + 0], v0);
        atomicAdd(&s_s[rt * 400 + c0 + 1], v1);
        atomicAdd(&s_s[rt * 400 + c0 + 2], v2);
        atomicAdd(&s_s[rt * 400 + c0 + 3], v3);
    }
}

// ---------------------------------------------------------------------------
// k5: y = relu(s_s@F1+b)@F2+b2. 8 blocks (b -> XCD b, matches kF's s_s[b]).
__global__ __launch_bounds__(256) void k5_final(
    const float* __restrict__ s_s, const float* __restrict__ F1_w,
    const float* __restrict__ F1_b, const float* __restrict__ F2_w,
    const float* __restrict__ F2_b, float* __restrict__ y)
{
    const int b = blockIdx.x;
    const int e = threadIdx.x;
    __shared__ float red[256];
    float val = 0.0f;
    if (e < 200) {
        float a = F1_b[e];
#pragma unroll 8
        for (int k = 0; k < 400; k++)
            a = fmaf(s_s[b * 400 + k], F1_w[(size_t)k * 200 + e], a);
        a = a > 0.0f ? a : 0.0f;
        val = a * F2_w[e];
    }
    red[e] = val;
    __syncthreads();
    for (int s = 128; s > 0; s >>= 1) {
        if (e < s) red[e] += red[e + s];
        __syncthreads();
    }
    if (e == 0) y[b] = red[0] + F2_b[0];
}

extern "C" void kernel_launch(void* const* d_in, const int* in_sizes, int n_in,
                              void* d_out, int out_size, void* d_ws, size_t ws_size,
                              hipStream_t stream)
{
    const int*   x     = (const int*)  d_in[0];
    const float* emb   = (const float*)d_in[1];
    const float* Wh_w  = (const float*)d_in[2];
    const float* Wh_b  = (const float*)d_in[3];
    const float* W1_w  = (const float*)d_in[4];
    const float* W2_w  = (const float*)d_in[5];
    const float* bvec  = (const float*)d_in[6];
    const float* cptr  = (const float*)d_in[7];
    const float* Wf1_w = (const float*)d_in[8];
    const float* Wf2_w = (const float*)d_in[9];
    const float* Wf2_b = (const float*)d_in[10];
    const float* Ws1_w = (const float*)d_in[11];
    const float* Ws1_b = (const float*)d_in[12];
    const float* Ws_w  = (const float*)d_in[13];
    const float* Ws_b  = (const float*)d_in[14];
    const float* F1_w  = (const float*)d_in[15];
    const float* F1_b  = (const float*)d_in[16];
    const float* F2_w  = (const float*)d_in[17];
    const float* F2_b  = (const float*)d_in[18];
    float* out = (float*)d_out;

    char* ws = (char*)d_ws;
    float*  xxT  = (float*) (ws + 0);          // 200*2112*4 = 1,689,600
    float*  hT   = (float*) (ws + 1689600);    // 1,689,600
    float4* attT = (float4*)(ws + 3379200);    // 1600*272*16 = 6,963,200
    float*  sfwT = (float*) (ws + 10342400);   // 1600*320*4 = 2,048,000
    float*  sbwT = (float*) (ws + 12390400);   // 2,048,000
    float*  uuT  = (float*) (ws + 14438400);   // 400*2112*4 = 3,379,200
    float*  t1T  = (float*) (ws + 17817600);   // 3,379,200
    float*  s_s  = (float*) (ws + 21196800);   // 12,800

    hipMemsetAsync(s_s, 0, 8 * 400 * sizeof(float), stream);

    hipLaunchKernelGGL(kA_gather, dim3(200),  dim3(256), 0, stream, x, emb, xxT);
    hipLaunchKernelGGL(kB_h,      dim3(800),  dim3(256), 0, stream, xxT, Wh_w, Wh_b, hT);
    hipLaunchKernelGGL(kC_h12,    dim3(800),  dim3(256), 0, stream,
                       hT, W1_w, W2_w, bvec, xxT, cptr, attT);
    hipLaunchKernelGGL(k2_attn,   dim3(1600), dim3(256), 0, stream,
                       attT, sfwT, sbwT);
    hipLaunchKernelGGL(kD_gate,   dim3(800),  dim3(256), 0, stream,
                       hT, sfwT, sbwT, Wf1_w, Wf2_w, Wf2_b, uuT);
    hipLaunchKernelGGL(kE_t1,     dim3(800),  dim3(256), 0, stream,
                       uuT, Ws1_w, Ws1_b, t1T);
    hipLaunchKernelGGL(kF_pool,   dim3(800),  dim3(256), 0, stream,
                       t1T, Ws_w, Ws_b, uuT, s_s);
    hipLaunchKernelGGL(k5_final,  dim3(8),    dim3(256), 0, stream,
                       s_s, F1_w, F1_b, F2_w, F2_b, out);
}